// Round 9
// baseline (81.089 us; speedup 1.0000x reference)
//
#include <hip/hip_runtime.h>
#include <math.h>

// LNCC, 3-kernel pipeline (barrier-free, LDS-free WH pass):
//  A: each thread owns a 2x4 (h,w) patch of one (b,d) slice. Loads its 10x12
//     reflected halo window (10 rows x 3 float4 x 2 arrays), permutes via
//     compile-time pm arrays for w-edge reflect, computes 5-channel W-window
//     sums per row (register sliding), accumulates rows into acc[5][2][4].
//     Writes u16 fixed-point WH sums (40 MB). No LDS, no barriers.
//     PATCH SIZE: 2x4 (not 4x4) — live set ~100 VGPR -> ~20 waves/CU. The
//     4x4 version needed 192 VGPR -> 10 waves/CU and sat at Occ 10%,
//     VALUBusy 25%, 54 us (R8: latency-bound).
//     REGISTER BUDGET: do NOT pass a min-waves hint: (256,3) capped at 84
//     VGPR, (256,2) at 128 — both spilled acc (R5: 862 MB, R6: 580 MB
//     scratch traffic).
//     EDGE REFLECT: w0==0 map is {4,3,2,1,0,1,2,3,4,5,6,7} — ALL entries
//     move (R7 bug: partial in-place permute).
//  B: D-pass sliding window on u16 (exact in fp32) + LNCC + block reduce.
//  C: deterministic double reduction -> d_out[0] = -mean.

#define NVOX 4194304        // 2*128*128*128
#define SLICE 16384         // 128*128
#define QSCALE (65535.0f / 81.0f)
#define DQ ((float)(81.0 / 65535.0 / 729.0))

__device__ __forceinline__ int refl(int p) {
    // reflect (no edge repeat) for dim 128; branchless: 127 - ||p| - 127|
    return 127 - abs(abs(p) - 127);
}

__global__ __launch_bounds__(256)
void lncc_wh_kernel(const float* __restrict__ f, const float* __restrict__ w,
                    unsigned short* __restrict__ buf) {
    // grid = 2048: slice = bid>>3 (0..255 = b*128+d), h-segment(16) = bid&7
    const int bid   = blockIdx.x;
    const int slice = bid >> 3;
    const int tid   = threadIdx.x;
    const int wg    = tid & 31;                       // w-group: w0 = 4*wg
    const int w0    = wg << 2;
    const int h0    = ((bid & 7) << 4) + ((tid >> 5) << 1);   // 2 rows/thread

    const float* fsl = f + (size_t)slice * SLICE;
    const float* wsl = w + (size_t)slice * SLICE;

    // aligned 12-col load base covering the (possibly reflected) window
    const int jbc  = (w0 == 0) ? 0 : ((w0 == 124) ? 116 : (w0 - 4));
    const int edge = (wg == 0) ? 1 : ((wg == 31) ? 2 : 0);

    float acc[5][2][4];
#pragma unroll
    for (int c = 0; c < 5; ++c)
#pragma unroll
        for (int k = 0; k < 2; ++k)
#pragma unroll
            for (int j = 0; j < 4; ++j) acc[c][k][j] = 0.f;

#pragma unroll
    for (int r = 0; r < 10; ++r) {
        const int rr = refl(h0 - 4 + r);
        const float* frow = fsl + rr * 128 + jbc;
        const float* wrow = wsl + rr * 128 + jbc;

        float Lf[12], Lw[12];
        *(float4*)&Lf[0] = *(const float4*)&frow[0];
        *(float4*)&Lf[4] = *(const float4*)&frow[4];
        *(float4*)&Lf[8] = *(const float4*)&frow[8];
        *(float4*)&Lw[0] = *(const float4*)&wrow[0];
        *(float4*)&Lw[4] = *(const float4*)&wrow[4];
        *(float4*)&Lw[8] = *(const float4*)&wrow[8];

        // window values for cols w0-4 .. w0+7 (reflected at edges):
        // pure register permutation, all indices compile-time after unroll
        float fv[12], wv[12];
        if (edge == 1) {           // w0==0: cols -4..7 -> {4,3,2,1,0,1,2,3,4,5,6,7}
            const int pm[12] = {4,3,2,1,0,1,2,3,4,5,6,7};
#pragma unroll
            for (int t = 0; t < 12; ++t) { fv[t] = Lf[pm[t]]; wv[t] = Lw[pm[t]]; }
        } else if (edge == 2) {    // w0==124: cols 120..131 -> {4..11,10,9,8,7}
            const int pm[12] = {4,5,6,7,8,9,10,11,10,9,8,7};
#pragma unroll
            for (int t = 0; t < 12; ++t) { fv[t] = Lf[pm[t]]; wv[t] = Lw[pm[t]]; }
        } else {
#pragma unroll
            for (int t = 0; t < 12; ++t) { fv[t] = Lf[t]; wv[t] = Lw[t]; }
        }

        // 5-channel 9-window sums for 4 outputs (register sliding)
        float rv[5][4];
        {
            float sf = 0.f, sw = 0.f, sff = 0.f, sww = 0.f, sfw = 0.f;
#pragma unroll
            for (int t = 0; t < 9; ++t) {
                sf += fv[t]; sw += wv[t];
                sff = fmaf(fv[t], fv[t], sff);
                sww = fmaf(wv[t], wv[t], sww);
                sfw = fmaf(fv[t], wv[t], sfw);
            }
            rv[0][0] = sf; rv[1][0] = sw; rv[2][0] = sff; rv[3][0] = sww; rv[4][0] = sfw;
#pragma unroll
            for (int k = 1; k < 4; ++k) {
                float fe = fv[k + 8], fx = fv[k - 1];
                float we = wv[k + 8], wx = wv[k - 1];
                sf += fe - fx; sw += we - wx;
                sff = fmaf(fe, fe, sff); sff = fmaf(-fx, fx, sff);
                sww = fmaf(we, we, sww); sww = fmaf(-wx, wx, sww);
                sfw = fmaf(fe, we, sfw); sfw = fmaf(-fx, wx, sfw);
                rv[0][k] = sf; rv[1][k] = sw; rv[2][k] = sff; rv[3][k] = sww; rv[4][k] = sfw;
            }
        }

        // loaded row r (abs h0-4+r) feeds out-row k iff k <= r <= k+8
#pragma unroll
        for (int k = 0; k < 2; ++k) {
            if (r >= k && r <= k + 8) {      // compile-time after unroll
#pragma unroll
                for (int c = 0; c < 5; ++c)
#pragma unroll
                    for (int j = 0; j < 4; ++j)
                        acc[c][k][j] += rv[c][j];
            }
        }
    }

    // quantize + store: 5 ch x 2 rows of ushort4 (8B, aligned)
#pragma unroll
    for (int c = 0; c < 5; ++c) {
        unsigned short* bc = buf + (size_t)c * NVOX + (size_t)slice * SLICE;
#pragma unroll
        for (int k = 0; k < 2; ++k) {
            ushort4 q;
            q.x = (unsigned short)fmaf(acc[c][k][0], QSCALE, 0.5f);
            q.y = (unsigned short)fmaf(acc[c][k][1], QSCALE, 0.5f);
            q.z = (unsigned short)fmaf(acc[c][k][2], QSCALE, 0.5f);
            q.w = (unsigned short)fmaf(acc[c][k][3], QSCALE, 0.5f);
            *(ushort4*)&bc[(size_t)(h0 + k) * 128 + w0] = q;
        }
    }
}

__global__ __launch_bounds__(256)
void lncc_d_kernel(const unsigned short* __restrict__ buf,
                   float* __restrict__ partials) {
    // 524288 threads: thread -> (b, dchunk(16), h, w), 8 d-outputs each
    const int gtid = blockIdx.x * 256 + threadIdx.x;
    const int wq = gtid & 127;
    const int h  = (gtid >> 7) & 127;
    const int dc = (gtid >> 14) & 15;
    const int b  = gtid >> 18;
    const int d0 = dc << 3;

    float s[5][8];
#pragma unroll
    for (int c = 0; c < 5; ++c) {
        const unsigned short* bc = buf + (size_t)c * NVOX
                                 + (size_t)b * (128 * SLICE)
                                 + (size_t)h * 128 + wq;
        float v[16];
#pragma unroll
        for (int t = 0; t < 16; ++t) {
            int d = refl(d0 - 4 + t);
            v[t] = (float)bc[(size_t)d * SLICE];
        }
        float acc = 0.f;
#pragma unroll
        for (int t = 0; t < 9; ++t) acc += v[t];
        s[c][0] = acc;
#pragma unroll
        for (int j = 1; j < 8; ++j) {
            acc += v[j + 8] - v[j - 1];
            s[c][j] = acc;
        }
    }

    float lsum = 0.f;
#pragma unroll
    for (int j = 0; j < 8; ++j) {
        float mf = s[0][j] * DQ;
        float mw = s[1][j] * DQ;
        float sgf = fmaxf(s[2][j] * DQ - mf * mf, 1e-8f);
        float sgw = fmaxf(s[3][j] * DQ - mw * mw, 1e-8f);
        float sfw = s[4][j] * DQ - mf * mw;
        float denom = fmaxf(sqrtf(fmaxf(sgf * sgw, 1e-16f)), 1e-8f);
        float l = sfw / denom;
        lsum += fminf(fmaxf(l, -10.f), 10.f);
    }

#pragma unroll
    for (int off = 32; off > 0; off >>= 1)
        lsum += __shfl_down(lsum, off, 64);
    __shared__ float red[4];
    int lane = threadIdx.x & 63, wid = threadIdx.x >> 6;
    if (lane == 0) red[wid] = lsum;
    __syncthreads();
    if (threadIdx.x == 0)
        partials[blockIdx.x] = red[0] + red[1] + red[2] + red[3];
}

__global__ __launch_bounds__(256)
void lncc_final_kernel(const float* __restrict__ partials, int n,
                       float* __restrict__ out) {
    __shared__ double rd[256];
    double acc = 0.0;
    for (int i = threadIdx.x; i < n; i += 256) acc += (double)partials[i];
    rd[threadIdx.x] = acc;
    __syncthreads();
    for (int s = 128; s > 0; s >>= 1) {
        if (threadIdx.x < s) rd[threadIdx.x] += rd[threadIdx.x + s];
        __syncthreads();
    }
    if (threadIdx.x == 0) out[0] = (float)(-rd[0] / (double)NVOX);
}

extern "C" void kernel_launch(void* const* d_in, const int* in_sizes, int n_in,
                              void* d_out, int out_size, void* d_ws, size_t ws_size,
                              hipStream_t stream) {
    const float* f = (const float*)d_in[0];
    const float* w = (const float*)d_in[1];
    float* out = (float*)d_out;

    unsigned short* buf = (unsigned short*)d_ws;                    // 40 MB
    float* partials = (float*)((char*)d_ws + (size_t)5 * NVOX * 2); // 2048 floats

    lncc_wh_kernel<<<2048, 256, 0, stream>>>(f, w, buf);
    lncc_d_kernel<<<2048, 256, 0, stream>>>(buf, partials);
    lncc_final_kernel<<<1, 256, 0, stream>>>(partials, 2048, out);
}

// Round 11
// 45.291 us; speedup vs baseline: 1.7904x; 1.7904x over previous
//
#include <hip/hip_runtime.h>
#include <math.h>

// LNCC as 4 streaming kernels, all kernel-B-style (no LDS, no barriers,
// 1-D register sliding, low VGPR, high occupancy — R3..R9 showed every
// 2-D-halo-per-thread variant is latency-bound at 10-25% VALU):
//  K1 W-pass: thread owns 8 w; float4 loads; 5ch slide; u16 quant x(65535/9).
//  K2 H-pass: thread owns 8h x 2w; 16 b32 loads/ch; INTEGER sliding (exact);
//             requantize /9 to u16. Channel loop rolled to keep ~60 VGPR.
//  K3 D-pass+LNCC: integer-exact D slide on u16, LNCC, block reduce.
//  C  deterministic double reduction -> d_out[0] = -mean.
// Quantization chain: Wq = round(Wsum*65535/9)            (Wsum <= 9)
//                     WHq = round(sum9(Wq)/9) ~= WHsum*65535/81  (<= 65535)
//                     Sd  = sum9(WHq) < 2^24 (exact in fp32)
//                     E[.] = Sd * 81/65535/729   <-- DQ3 (R10 bug: wrote 9/..,
//                     a 9x scale error on every moment; absmax 0.727)

#define NVOX 4194304        // 2*128*128*128
#define SLICE 16384         // 128*128
#define S1 (65535.0f / 9.0f)
#define DQ3 ((float)(81.0 / 65535.0 / 729.0))

__device__ __forceinline__ int refl(int p) {
    // reflect (no edge repeat) for dim 128
    return 127 - abs(abs(p) - 127);
}

__global__ __launch_bounds__(256)
void lncc_w_kernel(const float* __restrict__ f, const float* __restrict__ w,
                   unsigned short* __restrict__ wq) {
    // 524288 threads: thread -> (row = b*128*128 + d*128 + h, w-octet)
    const int gtid = blockIdx.x * 256 + threadIdx.x;
    const int wo  = gtid & 15;
    const int row = gtid >> 4;
    const int w0  = wo << 3;
    const int edge = (wo == 0) ? 1 : ((wo == 15) ? 2 : 0);
    const int jbc  = (edge == 1) ? 0 : ((edge == 2) ? 112 : (w0 - 4));

    const float* fr = f + (size_t)row * 128 + jbc;
    const float* wr = w + (size_t)row * 128 + jbc;
    float Lf[16], Lw[16];
#pragma unroll
    for (int t = 0; t < 4; ++t) {
        *(float4*)&Lf[4 * t] = *(const float4*)&fr[4 * t];
        *(float4*)&Lw[4 * t] = *(const float4*)&wr[4 * t];
    }
    // window cols w0-4 .. w0+11 (16 wide for 8 outputs), reflected at edges
    float fv[16], wv[16];
    if (edge == 1) {
        const int pm[16] = {4,3,2,1,0,1,2,3,4,5,6,7,8,9,10,11};
#pragma unroll
        for (int t = 0; t < 16; ++t) { fv[t] = Lf[pm[t]]; wv[t] = Lw[pm[t]]; }
    } else if (edge == 2) {
        const int pm[16] = {4,5,6,7,8,9,10,11,12,13,14,15,14,13,12,11};
#pragma unroll
        for (int t = 0; t < 16; ++t) { fv[t] = Lf[pm[t]]; wv[t] = Lw[pm[t]]; }
    } else {
#pragma unroll
        for (int t = 0; t < 16; ++t) { fv[t] = Lf[t]; wv[t] = Lw[t]; }
    }

    unsigned int q[5][8];
    float sf = 0.f, sw = 0.f, sff = 0.f, sww = 0.f, sfw = 0.f;
#pragma unroll
    for (int t = 0; t < 9; ++t) {
        sf += fv[t]; sw += wv[t];
        sff = fmaf(fv[t], fv[t], sff);
        sww = fmaf(wv[t], wv[t], sww);
        sfw = fmaf(fv[t], wv[t], sfw);
    }
    q[0][0] = (unsigned short)fmaf(sf,  S1, 0.5f);
    q[1][0] = (unsigned short)fmaf(sw,  S1, 0.5f);
    q[2][0] = (unsigned short)fmaf(sff, S1, 0.5f);
    q[3][0] = (unsigned short)fmaf(sww, S1, 0.5f);
    q[4][0] = (unsigned short)fmaf(sfw, S1, 0.5f);
#pragma unroll
    for (int k = 1; k < 8; ++k) {
        float fe = fv[k + 8], fx = fv[k - 1];
        float we = wv[k + 8], wx = wv[k - 1];
        sf += fe - fx; sw += we - wx;
        sff = fmaf(fe, fe, sff); sff = fmaf(-fx, fx, sff);
        sww = fmaf(we, we, sww); sww = fmaf(-wx, wx, sww);
        sfw = fmaf(fe, we, sfw); sfw = fmaf(-fx, wx, sfw);
        q[0][k] = (unsigned short)fmaf(sf,  S1, 0.5f);
        q[1][k] = (unsigned short)fmaf(sw,  S1, 0.5f);
        q[2][k] = (unsigned short)fmaf(sff, S1, 0.5f);
        q[3][k] = (unsigned short)fmaf(sww, S1, 0.5f);
        q[4][k] = (unsigned short)fmaf(sfw, S1, 0.5f);
    }
#pragma unroll
    for (int c = 0; c < 5; ++c) {
        uint4 P;
        P.x = q[c][0] | (q[c][1] << 16);
        P.y = q[c][2] | (q[c][3] << 16);
        P.z = q[c][4] | (q[c][5] << 16);
        P.w = q[c][6] | (q[c][7] << 16);
        *(uint4*)&wq[(size_t)c * NVOX + (size_t)row * 128 + w0] = P;
    }
}

__global__ __launch_bounds__(256)
void lncc_h_kernel(const unsigned short* __restrict__ wq,
                   unsigned short* __restrict__ whq) {
    // 262144 threads: thread -> (bd, h-octet, w-pair); integer sliding sums
    const int gtid = blockIdx.x * 256 + threadIdx.x;
    const int wp = gtid & 63;
    const int ho = (gtid >> 6) & 15;
    const int bd = gtid >> 10;              // b*128 + d
    const int h0 = ho << 3;

#pragma unroll 1                            // keep channels rolled: ~60 VGPR
    for (int c = 0; c < 5; ++c) {
        const unsigned short* base = wq + (size_t)c * NVOX + (size_t)bd * SLICE;
        unsigned short* ob = whq + (size_t)c * NVOX + (size_t)bd * SLICE;
        unsigned int v0[16], v1[16];
#pragma unroll
        for (int r = 0; r < 16; ++r) {
            int hh = refl(h0 - 4 + r);
            unsigned int pr = *(const unsigned int*)&base[(size_t)hh * 128 + 2 * wp];
            v0[r] = pr & 0xffffu;
            v1[r] = pr >> 16;
        }
        unsigned int s0 = 0, s1 = 0;
#pragma unroll
        for (int r = 0; r < 9; ++r) { s0 += v0[r]; s1 += v1[r]; }
#pragma unroll
        for (int k = 0; k < 8; ++k) {
            if (k > 0) { s0 += v0[k + 8] - v0[k - 1]; s1 += v1[k + 8] - v1[k - 1]; }
            unsigned int a = (unsigned short)fmaf((float)s0, 1.0f / 9.0f, 0.5f);
            unsigned int b = (unsigned short)fmaf((float)s1, 1.0f / 9.0f, 0.5f);
            *(unsigned int*)&ob[(size_t)(h0 + k) * 128 + 2 * wp] = a | (b << 16);
        }
    }
}

__global__ __launch_bounds__(256)
void lncc_d_kernel(const unsigned short* __restrict__ buf,
                   float* __restrict__ partials) {
    // 524288 threads: thread -> (b, dchunk(16), h, w), 8 d-outputs each
    const int gtid = blockIdx.x * 256 + threadIdx.x;
    const int wc = gtid & 127;
    const int h  = (gtid >> 7) & 127;
    const int dc = (gtid >> 14) & 15;
    const int b  = gtid >> 18;
    const int d0 = dc << 3;

    float s[5][8];
#pragma unroll
    for (int c = 0; c < 5; ++c) {
        const unsigned short* bc = buf + (size_t)c * NVOX
                                 + (size_t)b * (128 * SLICE)
                                 + (size_t)h * 128 + wc;
        float v[16];
#pragma unroll
        for (int t = 0; t < 16; ++t) {
            int d = refl(d0 - 4 + t);
            v[t] = (float)bc[(size_t)d * SLICE];
        }
        float acc = 0.f;
#pragma unroll
        for (int t = 0; t < 9; ++t) acc += v[t];
        s[c][0] = acc;
#pragma unroll
        for (int j = 1; j < 8; ++j) {
            acc += v[j + 8] - v[j - 1];
            s[c][j] = acc;
        }
    }

    float lsum = 0.f;
#pragma unroll
    for (int j = 0; j < 8; ++j) {
        float mf = s[0][j] * DQ3;
        float mw = s[1][j] * DQ3;
        float sgf = fmaxf(s[2][j] * DQ3 - mf * mf, 1e-8f);
        float sgw = fmaxf(s[3][j] * DQ3 - mw * mw, 1e-8f);
        float sfw = s[4][j] * DQ3 - mf * mw;
        float denom = fmaxf(sqrtf(fmaxf(sgf * sgw, 1e-16f)), 1e-8f);
        float l = sfw / denom;
        lsum += fminf(fmaxf(l, -10.f), 10.f);
    }

#pragma unroll
    for (int off = 32; off > 0; off >>= 1)
        lsum += __shfl_down(lsum, off, 64);
    __shared__ float red[4];
    int lane = threadIdx.x & 63, wid = threadIdx.x >> 6;
    if (lane == 0) red[wid] = lsum;
    __syncthreads();
    if (threadIdx.x == 0)
        partials[blockIdx.x] = red[0] + red[1] + red[2] + red[3];
}

__global__ __launch_bounds__(256)
void lncc_final_kernel(const float* __restrict__ partials, int n,
                       float* __restrict__ out) {
    __shared__ double rd[256];
    double acc = 0.0;
    for (int i = threadIdx.x; i < n; i += 256) acc += (double)partials[i];
    rd[threadIdx.x] = acc;
    __syncthreads();
    for (int s = 128; s > 0; s >>= 1) {
        if (threadIdx.x < s) rd[threadIdx.x] += rd[threadIdx.x + s];
        __syncthreads();
    }
    if (threadIdx.x == 0) out[0] = (float)(-rd[0] / (double)NVOX);
}

extern "C" void kernel_launch(void* const* d_in, const int* in_sizes, int n_in,
                              void* d_out, int out_size, void* d_ws, size_t ws_size,
                              hipStream_t stream) {
    const float* f = (const float*)d_in[0];
    const float* w = (const float*)d_in[1];
    float* out = (float*)d_out;

    unsigned short* wqb  = (unsigned short*)d_ws;                       // 40 MB
    unsigned short* whqb = wqb + (size_t)5 * NVOX;                      // 40 MB
    float* partials = (float*)((char*)d_ws + (size_t)20 * NVOX);        // 2048 f

    lncc_w_kernel<<<2048, 256, 0, stream>>>(f, w, wqb);
    lncc_h_kernel<<<1024, 256, 0, stream>>>(wqb, whqb);
    lncc_d_kernel<<<2048, 256, 0, stream>>>(whqb, partials);
    lncc_final_kernel<<<1, 256, 0, stream>>>(partials, 2048, out);
}